// Round 4
// baseline (652.588 us; speedup 1.0000x reference)
//
#include <hip/hip_runtime.h>
#include <math.h>

#define DI __device__ __forceinline__

constexpr int BB = 64;     // batch
constexpr int TT = 128;    // action steps (obs/rewards have TT+1)
constexpr int SS = 512;    // states
constexpr int AA = 16;     // actions
constexpr int OO = 4096;   // observations
constexpr float LOG2PI = 1.8378770664093453f;
constexpr float LOG4096 = 8.317766166719343f;  // log(16*256)

typedef float f32x4 __attribute__((ext_vector_type(4)));

// ---------------- fp8 e4m3fn converter (RTNE), x in [0, 448) ----------------
DI unsigned int f32_to_e4m3(float x) {
    unsigned int u = __float_as_uint(x);
    unsigned int lsb = (u >> 20) & 1u;
    unsigned int rounded = u + 0x7ffffu + lsb;          // RTNE into 3-bit mantissa
    int e8 = (int)(rounded >> 23) - 120;                // 127 - 7
    unsigned int m3 = (rounded >> 20) & 7u;
    unsigned int norm = ((unsigned int)e8 << 3) | m3;
    int sub = __float2int_rn(x * 512.0f);               // subnormal: multiples of 2^-9
    return (e8 <= 0) ? (unsigned int)sub : norm;
}

// ---------------- reduction helpers (wave64) ----------------
DI float bflyMax(float v) {
#pragma unroll
    for (int off = 32; off; off >>= 1) v = fmaxf(v, __shfl_xor(v, off));
    return v;
}
DI float bflySum(float v) {
#pragma unroll
    for (int off = 32; off; off >>= 1) v += __shfl_xor(v, off);
    return v;
}
DI float halfMax(float v) {
#pragma unroll
    for (int off = 16; off; off >>= 1) v = fmaxf(v, __shfl_xor(v, off));
    return v;
}
DI float halfSum(float v) {
#pragma unroll
    for (int off = 16; off; off >>= 1) v += __shfl_xor(v, off);
    return v;
}

template <int NW>
DI float blockMax(float v, float* wr) {
    v = bflyMax(v);
    const int lane = threadIdx.x & 63, wv = threadIdx.x >> 6;
    if (lane == 0) wr[wv] = v;
    __syncthreads();
    float r = wr[0];
#pragma unroll
    for (int i = 1; i < NW; ++i) r = fmaxf(r, wr[i]);
    __syncthreads();
    return r;
}
template <int NW>
DI float blockSum(float v, float* wr) {
    v = bflySum(v);
    const int lane = threadIdx.x & 63, wv = threadIdx.x >> 6;
    if (lane == 0) wr[wv] = v;
    __syncthreads();
    float r = wr[0];
#pragma unroll
    for (int i = 1; i < NW; ++i) r += wr[i];
    __syncthreads();
    return r;
}

// ---------------- precompute kernels ----------------

// Fused softmax + fp8 quantize (x256) + MFMA-B-fragment swizzle (same as R3).
__global__ __launch_bounds__(1024) void k_pack(const float* __restrict__ tl,
                                               unsigned char* __restrict__ PB) {
    __shared__ unsigned char lds[16384];
    const int a = blockIdx.x >> 4;
    const int kt = blockIdx.x & 15;
    const int tid = threadIdx.x;
    const int r = tid >> 5;       // 0..31
    const int nt = tid & 31;      // 0..31
    const int k = kt * 32 + r;
    const float* row = tl + ((size_t)a * SS + k) * SS + nt * 16;

    float x[16];
#pragma unroll
    for (int i = 0; i < 4; ++i) {
        float4 v = ((const float4*)row)[i];
        x[4 * i] = v.x; x[4 * i + 1] = v.y; x[4 * i + 2] = v.z; x[4 * i + 3] = v.w;
    }
    float mx = -INFINITY;
#pragma unroll
    for (int i = 0; i < 16; ++i) mx = fmaxf(mx, x[i]);
    mx = halfMax(mx);   // row lives in one 32-lane half
    float e[16];
    float sm = 0.f;
#pragma unroll
    for (int i = 0; i < 16; ++i) { e[i] = __expf(x[i] - mx); sm += e[i]; }
    sm = halfSum(sm);
    const float scale = 256.0f / sm;

    const int base = (nt >> 1) * 1024 + ((r >> 3) * 16) * 16 + (nt & 1) * 8 + (r & 7);
#pragma unroll
    for (int i = 0; i < 16; ++i) {
        lds[base + i * 16] = (unsigned char)f32_to_e4m3(e[i] * scale);
    }
    __syncthreads();

    ulonglong2* dst = (ulonglong2*)(PB + (size_t)(a * 16 + kt) * 16384);
    dst[tid] = ((const ulonglong2*)lds)[tid];
}

__global__ __launch_bounds__(256) void k_obs_stats(const float* __restrict__ ol,
                                                   float* __restrict__ mo,
                                                   float* __restrict__ lo) {
    __shared__ float wr[4];
    const int s = blockIdx.x;
    const float* in = ol + (size_t)s * OO;
    const int tid = threadIdx.x;
    float mx = -INFINITY;
    for (int i = tid; i < OO; i += 256) mx = fmaxf(mx, in[i]);
    float m = blockMax<4>(mx, wr);
    float sm = 0.f;
    for (int i = tid; i < OO; i += 256) sm += __expf(in[i] - m);
    float sum = blockSum<4>(sm, wr);
    if (tid == 0) { mo[s] = m; lo[s] = __logf(sum); }
}

__global__ __launch_bounds__(256) void k_obsT(const float* __restrict__ ol,
                                              const float* __restrict__ mo,
                                              const float* __restrict__ lo,
                                              float* __restrict__ obsT) {
    __shared__ float tile[64][65];
    const int tO = blockIdx.x % (OO / 64);
    const int tS = blockIdx.x / (OO / 64);
    const int o0 = tO * 64, s0 = tS * 64;
    const int cc = threadIdx.x & 63, rr = threadIdx.x >> 6;
#pragma unroll
    for (int j = 0; j < 16; ++j) {
        int r = rr + j * 4;
        tile[r][cc] = ol[(size_t)(s0 + r) * OO + o0 + cc] - mo[s0 + r] - lo[s0 + r];
    }
    __syncthreads();
#pragma unroll
    for (int j = 0; j < 16; ++j) {
        int r = rr + j * 4;
        obsT[(size_t)(o0 + r) * SS + s0 + cc] = tile[cc][r];
    }
}

// ---------------- main sequential-scan kernel ----------------
// one block per batch element, 512 threads = 8 waves, thread == state.
// 3 barriers per step; all invariant data preloaded to LDS/registers;
// next obsT row prefetched during the GEMV phase; empty k-tiles skipped
// (their fp8 p entries are exactly 0 -> zero contribution, bit-identical).
__global__ __launch_bounds__(512) void k_main(
    const float* __restrict__ regime, const int* __restrict__ obs,
    const float* __restrict__ rewards, const float* __restrict__ dones,
    const int* __restrict__ actions, const float* __restrict__ prior_logits,
    const unsigned char* __restrict__ PB, const float* __restrict__ obsT,
    const float* __restrict__ policy_logits, const float* __restrict__ r_mu,
    const float* __restrict__ r_logsig, float* __restrict__ out) {
    __shared__ float wrm[8], wrs[8];
    __shared__ unsigned long long p8q[64];   // 512 fp8 bytes of p*16
    __shared__ float lqprev[SS];
    __shared__ float polT_l[AA * SS];        // 32 KB
    __shared__ int obs_l[TT + 1];
    __shared__ float rew_l[TT + 1];
    __shared__ float done_l[TT + 1];
    __shared__ int act_l[TT];

    const int b = blockIdx.x;
    const int tid = threadIdx.x;
    const int wv = tid >> 6, lane = tid & 63, quad = lane >> 4;
    const int s = tid;

    // ---- one-time preloads ----
    if (tid <= TT) {
        obs_l[tid] = obs[tid * BB + b];
        rew_l[tid] = rewards[tid * BB + b];
        done_l[tid] = dones[tid * BB + b];
        if (tid < TT) act_l[tid] = actions[tid * BB + b];
    }
    {   // inline transposed log-softmax policy -> LDS
        const float4* pr4 = (const float4*)(policy_logits + (size_t)s * AA);
        float4 v0 = pr4[0], v1 = pr4[1], v2 = pr4[2], v3 = pr4[3];
        float xv[16] = {v0.x, v0.y, v0.z, v0.w, v1.x, v1.y, v1.z, v1.w,
                        v2.x, v2.y, v2.z, v2.w, v3.x, v3.y, v3.z, v3.w};
        float mx = xv[0];
#pragma unroll
        for (int i = 1; i < 16; ++i) mx = fmaxf(mx, xv[i]);
        float sm = 0.f;
#pragma unroll
        for (int i = 0; i < 16; ++i) sm += __expf(xv[i] - mx);
        float ls = mx + __logf(sm);
#pragma unroll
        for (int a = 0; a < AA; ++a) polT_l[a * SS + s] = xv[a] - ls;
    }
    const float rm = r_mu[s];
    const float rls = r_logsig[s];
    const float inv_sig = __expf(-rls);
    const float reg = regime[b];

    // inline prior log-softmax (barriers inside also publish the preloads)
    float px = prior_logits[s];
    float pm = blockMax<8>(px, wrm);
    float pe = __expf(px - pm);
    float psum = blockSum<8>(pe, wrs);
    const float prior_reg = px - pm - __logf(psum);

    // prefetch obsT row for t=0 (obs_l visible after blockMax's barrier)
    float obsv = obsT[(size_t)obs_l[0] * SS + s];

    float log_prob = 0.f;
    float was_done = 0.f;

    for (int t = 0; t <= TT; ++t) {
        const float r = rew_l[t];
        int a = 0;
        float d = 0.f;
        if (t < TT) { a = act_l[t]; d = done_l[t]; }
        const float done = fmaxf(was_done, d);

        float diff = (r - rm) * inv_sig;
        float emis = obsv - 0.5f * diff * diff - rls - 0.5f * LOG2PI;
        float base_in = (t == 0) ? prior_reg : lqprev[s];
        float la = 0.f;
        if (t < TT) {
            la = polT_l[a * SS + s];
            if (done == 1.0f || reg == 1.0f) la = 0.f;
        }
        float lq = base_in + emis + la;

        // block max: wave butterfly + ONE barrier
        float wm = bflyMax(lq);
        if (lane == 0) wrm[wv] = wm;
        __syncthreads();  // B1
        float m = wrm[0];
#pragma unroll
        for (int i = 1; i < 8; ++i) m = fmaxf(m, wrm[i]);

        float ex = __expf(lq - m);
        ((unsigned char*)p8q)[s] = (unsigned char)f32_to_e4m3(ex * 16.0f);
        float wsum = bflySum(ex);
        if (lane == 0) wrs[wv] = wsum;
        __syncthreads();  // B2 (also publishes p8q)
        float sum = wrs[0];
#pragma unroll
        for (int i = 1; i < 8; ++i) sum += wrs[i];
        float lse = m + __logf(sum);
        float lq_orda = lse * (1.0f - was_done);
        if (!isinf(log_prob)) log_prob += lq_orda;

        if (t == TT) break;
        was_done = done;

        // prefetch next obsT row (consumed after B3 next iteration)
        float obsv_next = obsT[(size_t)obs_l[t + 1] * SS + s];

        // GEMV via fp8 MFMA; wave wv owns columns 64*wv .. 64*wv+63
        const float basev = m - lq_orda - LOG4096;
        const ulonglong2* PBa = (const ulonglong2*)(PB + (size_t)a * (SS * SS));
        f32x4 acc0 = {0.f, 0.f, 0.f, 0.f};
        f32x4 acc1 = {0.f, 0.f, 0.f, 0.f};
        f32x4 acc2 = {0.f, 0.f, 0.f, 0.f};
        f32x4 acc3 = {0.f, 0.f, 0.f, 0.f};
#pragma unroll
        for (int kt = 0; kt < 16; ++kt) {
            long afrag = (long)p8q[kt * 4 + quad];   // LDS broadcast per quad
            if (__any(afrag != 0)) {                 // wave-uniform skip of empty ktile
                ulonglong2 bf0 = PBa[(kt * 16 + 2 * wv) * 64 + lane];
                ulonglong2 bf1 = PBa[(kt * 16 + 2 * wv + 1) * 64 + lane];
                acc0 = __builtin_amdgcn_mfma_f32_16x16x32_fp8_fp8((long)bf0.x, afrag, acc0, 0, 0, 0);
                acc1 = __builtin_amdgcn_mfma_f32_16x16x32_fp8_fp8((long)bf0.y, afrag, acc1, 0, 0, 0);
                acc2 = __builtin_amdgcn_mfma_f32_16x16x32_fp8_fp8((long)bf1.x, afrag, acc2, 0, 0, 0);
                acc3 = __builtin_amdgcn_mfma_f32_16x16x32_fp8_fp8((long)bf1.y, afrag, acc3, 0, 0, 0);
            }
        }
        if (lane < 16) {
            lqprev[wv * 64 + lane]      = basev + __logf(acc0[0]);
            lqprev[wv * 64 + 16 + lane] = basev + __logf(acc1[0]);
            lqprev[wv * 64 + 32 + lane] = basev + __logf(acc2[0]);
            lqprev[wv * 64 + 48 + lane] = basev + __logf(acc3[0]);
        }
        __syncthreads();  // B3
        obsv = obsv_next;
    }

    if (tid == 0) out[b] = log_prob;
}

// ---------------- launch ----------------
extern "C" void kernel_launch(void* const* d_in, const int* in_sizes, int n_in,
                              void* d_out, int out_size, void* d_ws, size_t ws_size,
                              hipStream_t stream) {
    const float* regime = (const float*)d_in[0];
    const int* obs = (const int*)d_in[1];
    const float* rewards = (const float*)d_in[2];
    const float* dones = (const float*)d_in[3];
    const int* actions = (const int*)d_in[4];
    const float* prior_logits = (const float*)d_in[5];
    const float* trans_logits = (const float*)d_in[6];
    const float* obs_logits = (const float*)d_in[7];
    const float* policy_logits = (const float*)d_in[8];
    const float* r_mu = (const float*)d_in[9];
    const float* r_logsig = (const float*)d_in[10];
    float* out = (float*)d_out;

    char* ws = (char*)d_ws;
    unsigned char* PB = (unsigned char*)ws;                    // A*S*S fp8 = 4 MB
    float* obsT = (float*)(ws + (size_t)AA * SS * SS);         // O*S fp32 = 8 MB
    float* mo = (float*)(ws + (size_t)AA * SS * SS + (size_t)OO * SS * 4);  // S
    float* lo = mo + SS;                                       // S

    k_pack<<<256, 1024, 0, stream>>>(trans_logits, PB);
    k_obs_stats<<<SS, 256, 0, stream>>>(obs_logits, mo, lo);
    k_obsT<<<(OO / 64) * (SS / 64), 256, 0, stream>>>(obs_logits, mo, lo, obsT);
    k_main<<<BB, 512, 0, stream>>>(regime, obs, rewards, dones, actions, prior_logits,
                                   PB, obsT, policy_logits, r_mu, r_logsig, out);
}

// Round 5
// 606.480 us; speedup vs baseline: 1.0760x; 1.0760x over previous
//
#include <hip/hip_runtime.h>
#include <math.h>

#define DI __device__ __forceinline__

constexpr int BB = 64;     // batch
constexpr int TT = 128;    // action steps (obs/rewards have TT+1)
constexpr int SS = 512;    // states
constexpr int AA = 16;     // actions
constexpr int OO = 4096;   // observations
constexpr float LOG2PI = 1.8378770664093453f;
constexpr float LOG4096 = 8.317766166719343f;  // log(16*256)

typedef float f32x4 __attribute__((ext_vector_type(4)));

// LDS-only barrier: does NOT drain vmcnt, so prefetched global loads stay in
// flight across it (CK block_sync_lds idiom). All cross-thread traffic in
// k_main is LDS, so lgkmcnt(0)+barrier is sufficient.
DI void lds_barrier() {
    asm volatile("s_waitcnt lgkmcnt(0)\n\ts_barrier" ::: "memory");
}

// ---------------- fp8 e4m3fn converter (RTNE), x in [0, 448) ----------------
DI unsigned int f32_to_e4m3(float x) {
    unsigned int u = __float_as_uint(x);
    unsigned int lsb = (u >> 20) & 1u;
    unsigned int rounded = u + 0x7ffffu + lsb;          // RTNE into 3-bit mantissa
    int e8 = (int)(rounded >> 23) - 120;                // 127 - 7
    unsigned int m3 = (rounded >> 20) & 7u;
    unsigned int norm = ((unsigned int)e8 << 3) | m3;
    int sub = __float2int_rn(x * 512.0f);               // subnormal: multiples of 2^-9
    return (e8 <= 0) ? (unsigned int)sub : norm;
}

// ---------------- reduction helpers (wave64) ----------------
DI float bflyMax(float v) {
#pragma unroll
    for (int off = 32; off; off >>= 1) v = fmaxf(v, __shfl_xor(v, off));
    return v;
}
DI float bflySum(float v) {
#pragma unroll
    for (int off = 32; off; off >>= 1) v += __shfl_xor(v, off);
    return v;
}
DI float halfMax(float v) {
#pragma unroll
    for (int off = 16; off; off >>= 1) v = fmaxf(v, __shfl_xor(v, off));
    return v;
}
DI float halfSum(float v) {
#pragma unroll
    for (int off = 16; off; off >>= 1) v += __shfl_xor(v, off);
    return v;
}

template <int NW>
DI float blockMax(float v, float* wr) {
    v = bflyMax(v);
    const int lane = threadIdx.x & 63, wv = threadIdx.x >> 6;
    if (lane == 0) wr[wv] = v;
    __syncthreads();
    float r = wr[0];
#pragma unroll
    for (int i = 1; i < NW; ++i) r = fmaxf(r, wr[i]);
    __syncthreads();
    return r;
}
template <int NW>
DI float blockSum(float v, float* wr) {
    v = bflySum(v);
    const int lane = threadIdx.x & 63, wv = threadIdx.x >> 6;
    if (lane == 0) wr[wv] = v;
    __syncthreads();
    float r = wr[0];
#pragma unroll
    for (int i = 1; i < NW; ++i) r += wr[i];
    __syncthreads();
    return r;
}

// ---------------- precompute kernels ----------------

// Fused softmax + fp8 quantize (x256) + MFMA-B-fragment swizzle (same as R3/R4).
__global__ __launch_bounds__(1024) void k_pack(const float* __restrict__ tl,
                                               unsigned char* __restrict__ PB) {
    __shared__ unsigned char lds[16384];
    const int a = blockIdx.x >> 4;
    const int kt = blockIdx.x & 15;
    const int tid = threadIdx.x;
    const int r = tid >> 5;       // 0..31
    const int nt = tid & 31;      // 0..31
    const int k = kt * 32 + r;
    const float* row = tl + ((size_t)a * SS + k) * SS + nt * 16;

    float x[16];
#pragma unroll
    for (int i = 0; i < 4; ++i) {
        float4 v = ((const float4*)row)[i];
        x[4 * i] = v.x; x[4 * i + 1] = v.y; x[4 * i + 2] = v.z; x[4 * i + 3] = v.w;
    }
    float mx = -INFINITY;
#pragma unroll
    for (int i = 0; i < 16; ++i) mx = fmaxf(mx, x[i]);
    mx = halfMax(mx);
    float e[16];
    float sm = 0.f;
#pragma unroll
    for (int i = 0; i < 16; ++i) { e[i] = __expf(x[i] - mx); sm += e[i]; }
    sm = halfSum(sm);
    const float scale = 256.0f / sm;

    const int base = (nt >> 1) * 1024 + ((r >> 3) * 16) * 16 + (nt & 1) * 8 + (r & 7);
#pragma unroll
    for (int i = 0; i < 16; ++i) {
        lds[base + i * 16] = (unsigned char)f32_to_e4m3(e[i] * scale);
    }
    __syncthreads();

    ulonglong2* dst = (ulonglong2*)(PB + (size_t)(a * 16 + kt) * 16384);
    dst[tid] = ((const ulonglong2*)lds)[tid];
}

__global__ __launch_bounds__(256) void k_obs_stats(const float* __restrict__ ol,
                                                   float* __restrict__ mo,
                                                   float* __restrict__ lo) {
    __shared__ float wr[4];
    const int s = blockIdx.x;
    const float* in = ol + (size_t)s * OO;
    const int tid = threadIdx.x;
    float mx = -INFINITY;
    for (int i = tid; i < OO; i += 256) mx = fmaxf(mx, in[i]);
    float m = blockMax<4>(mx, wr);
    float sm = 0.f;
    for (int i = tid; i < OO; i += 256) sm += __expf(in[i] - m);
    float sum = blockSum<4>(sm, wr);
    if (tid == 0) { mo[s] = m; lo[s] = __logf(sum); }
}

__global__ __launch_bounds__(256) void k_obsT(const float* __restrict__ ol,
                                              const float* __restrict__ mo,
                                              const float* __restrict__ lo,
                                              float* __restrict__ obsT) {
    __shared__ float tile[64][65];
    const int tO = blockIdx.x % (OO / 64);
    const int tS = blockIdx.x / (OO / 64);
    const int o0 = tO * 64, s0 = tS * 64;
    const int cc = threadIdx.x & 63, rr = threadIdx.x >> 6;
#pragma unroll
    for (int j = 0; j < 16; ++j) {
        int r = rr + j * 4;
        tile[r][cc] = ol[(size_t)(s0 + r) * OO + o0 + cc] - mo[s0 + r] - lo[s0 + r];
    }
    __syncthreads();
#pragma unroll
    for (int j = 0; j < 16; ++j) {
        int r = rr + j * 4;
        obsT[(size_t)(o0 + r) * SS + s0 + cc] = tile[cc][r];
    }
}

// ---------------- main sequential-scan kernel ----------------
// one block per batch element, 512 threads = 8 waves, thread == state.
// Per step:
//   pre-B1: lq, wave max, conservative nonzero-ktile ballot
//   B1 (lds-only barrier, no vmcnt drain)
//   block max; BURST-issue all P-fragment loads for live ktiles (stay in
//     flight through phase A); prefetch next obsT row
//   exp, fp8-quantize p into LDS, wave sum
//   B2; lse, log_prob update
//   MFMA over live ktiles (fragments already arriving), log, write lqprev
//   B3
// The ktile skip is bit-exact: a ktile is dropped only if every state in it
// has lq - wavemax < -9.75 < -14*ln2 + (m - wavemax <= 0), which forces its
// fp8 p-bytes to exactly 0 -> zero contribution.
__global__ __launch_bounds__(512, 2) void k_main(
    const float* __restrict__ regime, const int* __restrict__ obs,
    const float* __restrict__ rewards, const float* __restrict__ dones,
    const int* __restrict__ actions, const float* __restrict__ prior_logits,
    const unsigned char* __restrict__ PB, const float* __restrict__ obsT,
    const float* __restrict__ policy_logits, const float* __restrict__ r_mu,
    const float* __restrict__ r_logsig, float* __restrict__ out) {
    __shared__ float wrm[8], wrs[8];
    __shared__ unsigned int ktw[8];
    __shared__ unsigned char p8[4 * 144 + 16];  // [quad][16 ktiles x 8B], pad 144 -> no bank conflict
    __shared__ float lqprev[SS];
    __shared__ float polT_l[AA * SS];           // 32 KB
    __shared__ int obs_l[TT + 1];
    __shared__ float rew_l[TT + 1];
    __shared__ float done_l[TT + 1];
    __shared__ int act_l[TT];

    const int b = blockIdx.x;
    const int tid = threadIdx.x;
    const int wv = tid >> 6, lane = tid & 63, quad = lane >> 4;
    const int s = tid;

    // ---- one-time preloads ----
    if (tid <= TT) {
        obs_l[tid] = obs[tid * BB + b];
        rew_l[tid] = rewards[tid * BB + b];
        done_l[tid] = dones[tid * BB + b];
        if (tid < TT) act_l[tid] = actions[tid * BB + b];
    }
    {   // inline transposed log-softmax policy -> LDS
        const float4* pr4 = (const float4*)(policy_logits + (size_t)s * AA);
        float4 v0 = pr4[0], v1 = pr4[1], v2 = pr4[2], v3 = pr4[3];
        float xv[16] = {v0.x, v0.y, v0.z, v0.w, v1.x, v1.y, v1.z, v1.w,
                        v2.x, v2.y, v2.z, v2.w, v3.x, v3.y, v3.z, v3.w};
        float mx = xv[0];
#pragma unroll
        for (int i = 1; i < 16; ++i) mx = fmaxf(mx, xv[i]);
        float sm = 0.f;
#pragma unroll
        for (int i = 0; i < 16; ++i) sm += __expf(xv[i] - mx);
        float ls = mx + __logf(sm);
#pragma unroll
        for (int a = 0; a < AA; ++a) polT_l[a * SS + s] = xv[a] - ls;
    }
    const float rm = r_mu[s];
    const float rls = r_logsig[s];
    const float inv_sig = __expf(-rls);
    const float reg = regime[b];

    // inline prior log-softmax (its barriers also publish the preloads)
    float px = prior_logits[s];
    {
        float wm0 = bflyMax(px);
        if (lane == 0) wrm[wv] = wm0;
    }
    lds_barrier();
    float pm = wrm[0];
#pragma unroll
    for (int i = 1; i < 8; ++i) pm = fmaxf(pm, wrm[i]);
    {
        float ws0 = bflySum(__expf(px - pm));
        if (lane == 0) wrs[wv] = ws0;
    }
    lds_barrier();
    float psum = wrs[0];
#pragma unroll
    for (int i = 1; i < 8; ++i) psum += wrs[i];
    const float prior_reg = px - pm - __logf(psum);

    // prefetch obsT row for t=0
    float obsv = obsT[(size_t)obs_l[0] * SS + s];

    float log_prob = 0.f;
    float was_done = 0.f;

    for (int t = 0; t < TT; ++t) {
        const float r = rew_l[t];
        const int a = act_l[t];
        const float d = done_l[t];
        const float done = fmaxf(was_done, d);

        float diff = (r - rm) * inv_sig;
        float emis = obsv - 0.5f * diff * diff - rls - 0.5f * LOG2PI;
        float base_in = (t == 0) ? prior_reg : lqprev[s];
        float la = polT_l[a * SS + s];
        if (done == 1.0f || reg == 1.0f) la = 0.f;
        float lq = base_in + emis + la;

        float wmax = bflyMax(lq);
        unsigned long long bal = __ballot((lq - wmax) >= -9.75f);
        if (lane == 0) {
            wrm[wv] = wmax;
            ktw[wv] = ((bal & 0xFFFFFFFFull) ? 1u : 0u) | ((bal >> 32) ? 2u : 0u);
        }
        lds_barrier();  // B1

        float m = wrm[0];
#pragma unroll
        for (int i = 1; i < 8; ++i) m = fmaxf(m, wrm[i]);
        unsigned kmask = ktw[0] | (ktw[1] << 2) | (ktw[2] << 4) | (ktw[3] << 6) |
                         (ktw[4] << 8) | (ktw[5] << 10) | (ktw[6] << 12) | (ktw[7] << 14);
        kmask = __builtin_amdgcn_readfirstlane(kmask);

        // burst-issue P-fragment loads for live ktiles; they stay in flight
        // through phase A (lds_barrier does not drain vmcnt)
        const ulonglong2* PBa = (const ulonglong2*)(PB + (size_t)a * (SS * SS));
        ulonglong2 bfA[16], bfB[16];
#pragma unroll
        for (int kt = 0; kt < 16; ++kt) {
            if (kmask & (1u << kt)) {
                bfA[kt] = PBa[(kt * 16 + 2 * wv) * 64 + lane];
                bfB[kt] = PBa[(kt * 16 + 2 * wv + 1) * 64 + lane];
            }
        }
        // prefetch next obsT row (used next iteration)
        float obsv_next = obsT[(size_t)obs_l[t + 1] * SS + s];

        float ex = __expf(lq - m);
        p8[((s >> 3) & 3) * 144 + (s >> 5) * 8 + (s & 7)] =
            (unsigned char)f32_to_e4m3(ex * 16.0f);
        float wsum = bflySum(ex);
        if (lane == 0) wrs[wv] = wsum;
        lds_barrier();  // B2 (publishes p8)

        float sum = wrs[0];
#pragma unroll
        for (int i = 1; i < 8; ++i) sum += wrs[i];
        float lse = m + __logf(sum);
        float lq_orda = lse * (1.0f - was_done);
        if (!isinf(log_prob)) log_prob += lq_orda;
        was_done = done;

        const float basev = m - lq_orda - LOG4096;
        f32x4 acc0 = {0.f, 0.f, 0.f, 0.f};
        f32x4 acc1 = {0.f, 0.f, 0.f, 0.f};
        f32x4 acc2 = {0.f, 0.f, 0.f, 0.f};
        f32x4 acc3 = {0.f, 0.f, 0.f, 0.f};
#pragma unroll
        for (int kt = 0; kt < 16; ++kt) {
            if (kmask & (1u << kt)) {
                long af = *(const long long*)(p8 + quad * 144 + kt * 8);
                acc0 = __builtin_amdgcn_mfma_f32_16x16x32_fp8_fp8((long)bfA[kt].x, af, acc0, 0, 0, 0);
                acc1 = __builtin_amdgcn_mfma_f32_16x16x32_fp8_fp8((long)bfA[kt].y, af, acc1, 0, 0, 0);
                acc2 = __builtin_amdgcn_mfma_f32_16x16x32_fp8_fp8((long)bfB[kt].x, af, acc2, 0, 0, 0);
                acc3 = __builtin_amdgcn_mfma_f32_16x16x32_fp8_fp8((long)bfB[kt].y, af, acc3, 0, 0, 0);
            }
        }
        if (lane < 16) {
            lqprev[wv * 64 + lane]      = basev + __logf(acc0[0]);
            lqprev[wv * 64 + 16 + lane] = basev + __logf(acc1[0]);
            lqprev[wv * 64 + 32 + lane] = basev + __logf(acc2[0]);
            lqprev[wv * 64 + 48 + lane] = basev + __logf(acc3[0]);
        }
        lds_barrier();  // B3
        obsv = obsv_next;
    }

    // final step t = TT (no action term, no transition)
    {
        const float r = rew_l[TT];
        float diff = (r - rm) * inv_sig;
        float emis = obsv - 0.5f * diff * diff - rls - 0.5f * LOG2PI;
        float lq = lqprev[s] + emis;
        float wmax = bflyMax(lq);
        if (lane == 0) wrm[wv] = wmax;
        lds_barrier();
        float m = wrm[0];
#pragma unroll
        for (int i = 1; i < 8; ++i) m = fmaxf(m, wrm[i]);
        float wsum = bflySum(__expf(lq - m));
        if (lane == 0) wrs[wv] = wsum;
        lds_barrier();
        float sum = wrs[0];
#pragma unroll
        for (int i = 1; i < 8; ++i) sum += wrs[i];
        float lse = m + __logf(sum);
        float lq_ord = lse * (1.0f - was_done);
        if (!isinf(log_prob)) log_prob += lq_ord;
    }

    if (tid == 0) out[b] = log_prob;
}

// ---------------- launch ----------------
extern "C" void kernel_launch(void* const* d_in, const int* in_sizes, int n_in,
                              void* d_out, int out_size, void* d_ws, size_t ws_size,
                              hipStream_t stream) {
    const float* regime = (const float*)d_in[0];
    const int* obs = (const int*)d_in[1];
    const float* rewards = (const float*)d_in[2];
    const float* dones = (const float*)d_in[3];
    const int* actions = (const int*)d_in[4];
    const float* prior_logits = (const float*)d_in[5];
    const float* trans_logits = (const float*)d_in[6];
    const float* obs_logits = (const float*)d_in[7];
    const float* policy_logits = (const float*)d_in[8];
    const float* r_mu = (const float*)d_in[9];
    const float* r_logsig = (const float*)d_in[10];
    float* out = (float*)d_out;

    char* ws = (char*)d_ws;
    unsigned char* PB = (unsigned char*)ws;                    // A*S*S fp8 = 4 MB
    float* obsT = (float*)(ws + (size_t)AA * SS * SS);         // O*S fp32 = 8 MB
    float* mo = (float*)(ws + (size_t)AA * SS * SS + (size_t)OO * SS * 4);  // S
    float* lo = mo + SS;                                       // S

    k_pack<<<256, 1024, 0, stream>>>(trans_logits, PB);
    k_obs_stats<<<SS, 256, 0, stream>>>(obs_logits, mo, lo);
    k_obsT<<<(OO / 64) * (SS / 64), 256, 0, stream>>>(obs_logits, mo, lo, obsT);
    k_main<<<BB, 512, 0, stream>>>(regime, obs, rewards, dones, actions, prior_logits,
                                   PB, obsT, policy_logits, r_mu, r_logsig, out);
}

// Round 6
// 568.631 us; speedup vs baseline: 1.1476x; 1.0666x over previous
//
#include <hip/hip_runtime.h>
#include <math.h>

#define DI __device__ __forceinline__

constexpr int BB = 64;     // batch
constexpr int TT = 128;    // action steps (obs/rewards have TT+1)
constexpr int SS = 512;    // states
constexpr int AA = 16;     // actions
constexpr int OO = 4096;   // observations
constexpr float LOG2PI = 1.8378770664093453f;
constexpr float LOG4096 = 8.317766166719343f;  // log(16*256)

typedef float f32x4 __attribute__((ext_vector_type(4)));

// LDS-only barrier: does NOT drain vmcnt, so in-flight global loads survive.
// All cross-thread traffic in k_main is LDS-only.
DI void lds_barrier() {
    asm volatile("s_waitcnt lgkmcnt(0)\n\ts_barrier" ::: "memory");
}

// ---------------- fp8 e4m3fn converter (RTNE), x in [0, 448) ----------------
DI unsigned int f32_to_e4m3(float x) {
    unsigned int u = __float_as_uint(x);
    unsigned int lsb = (u >> 20) & 1u;
    unsigned int rounded = u + 0x7ffffu + lsb;          // RTNE into 3-bit mantissa
    int e8 = (int)(rounded >> 23) - 120;                // 127 - 7
    unsigned int m3 = (rounded >> 20) & 7u;
    unsigned int norm = ((unsigned int)e8 << 3) | m3;
    int sub = __float2int_rn(x * 512.0f);               // subnormal: multiples of 2^-9
    return (e8 <= 0) ? (unsigned int)sub : norm;
}

// ---------------- reduction helpers (wave64) ----------------
DI float bflyMax(float v) {
#pragma unroll
    for (int off = 32; off; off >>= 1) v = fmaxf(v, __shfl_xor(v, off));
    return v;
}
DI float bflySum(float v) {
#pragma unroll
    for (int off = 32; off; off >>= 1) v += __shfl_xor(v, off);
    return v;
}
DI float halfMax(float v) {
#pragma unroll
    for (int off = 16; off; off >>= 1) v = fmaxf(v, __shfl_xor(v, off));
    return v;
}
DI float halfSum(float v) {
#pragma unroll
    for (int off = 16; off; off >>= 1) v += __shfl_xor(v, off);
    return v;
}

template <int NW>
DI float blockMax(float v, float* wr) {
    v = bflyMax(v);
    const int lane = threadIdx.x & 63, wv = threadIdx.x >> 6;
    if (lane == 0) wr[wv] = v;
    __syncthreads();
    float r = wr[0];
#pragma unroll
    for (int i = 1; i < NW; ++i) r = fmaxf(r, wr[i]);
    __syncthreads();
    return r;
}
template <int NW>
DI float blockSum(float v, float* wr) {
    v = bflySum(v);
    const int lane = threadIdx.x & 63, wv = threadIdx.x >> 6;
    if (lane == 0) wr[wv] = v;
    __syncthreads();
    float r = wr[0];
#pragma unroll
    for (int i = 1; i < NW; ++i) r += wr[i];
    __syncthreads();
    return r;
}

// ---------------- precompute kernels ----------------

// Fused softmax + fp8 quantize (x256) + MFMA-B-fragment swizzle (same as R3-R5).
__global__ __launch_bounds__(1024) void k_pack(const float* __restrict__ tl,
                                               unsigned char* __restrict__ PB) {
    __shared__ unsigned char lds[16384];
    const int a = blockIdx.x >> 4;
    const int kt = blockIdx.x & 15;
    const int tid = threadIdx.x;
    const int r = tid >> 5;       // 0..31
    const int nt = tid & 31;      // 0..31
    const int k = kt * 32 + r;
    const float* row = tl + ((size_t)a * SS + k) * SS + nt * 16;

    float x[16];
#pragma unroll
    for (int i = 0; i < 4; ++i) {
        float4 v = ((const float4*)row)[i];
        x[4 * i] = v.x; x[4 * i + 1] = v.y; x[4 * i + 2] = v.z; x[4 * i + 3] = v.w;
    }
    float mx = -INFINITY;
#pragma unroll
    for (int i = 0; i < 16; ++i) mx = fmaxf(mx, x[i]);
    mx = halfMax(mx);
    float e[16];
    float sm = 0.f;
#pragma unroll
    for (int i = 0; i < 16; ++i) { e[i] = __expf(x[i] - mx); sm += e[i]; }
    sm = halfSum(sm);
    const float scale = 256.0f / sm;

    const int base = (nt >> 1) * 1024 + ((r >> 3) * 16) * 16 + (nt & 1) * 8 + (r & 7);
#pragma unroll
    for (int i = 0; i < 16; ++i) {
        lds[base + i * 16] = (unsigned char)f32_to_e4m3(e[i] * scale);
    }
    __syncthreads();

    ulonglong2* dst = (ulonglong2*)(PB + (size_t)(a * 16 + kt) * 16384);
    dst[tid] = ((const ulonglong2*)lds)[tid];
}

__global__ __launch_bounds__(256) void k_obs_stats(const float* __restrict__ ol,
                                                   float* __restrict__ mo,
                                                   float* __restrict__ lo) {
    __shared__ float wr[4];
    const int s = blockIdx.x;
    const float* in = ol + (size_t)s * OO;
    const int tid = threadIdx.x;
    float mx = -INFINITY;
    for (int i = tid; i < OO; i += 256) mx = fmaxf(mx, in[i]);
    float m = blockMax<4>(mx, wr);
    float sm = 0.f;
    for (int i = tid; i < OO; i += 256) sm += __expf(in[i] - m);
    float sum = blockSum<4>(sm, wr);
    if (tid == 0) { mo[s] = m; lo[s] = __logf(sum); }
}

__global__ __launch_bounds__(256) void k_obsT(const float* __restrict__ ol,
                                              const float* __restrict__ mo,
                                              const float* __restrict__ lo,
                                              float* __restrict__ obsT) {
    __shared__ float tile[64][65];
    const int tO = blockIdx.x % (OO / 64);
    const int tS = blockIdx.x / (OO / 64);
    const int o0 = tO * 64, s0 = tS * 64;
    const int cc = threadIdx.x & 63, rr = threadIdx.x >> 6;
#pragma unroll
    for (int j = 0; j < 16; ++j) {
        int r = rr + j * 4;
        tile[r][cc] = ol[(size_t)(s0 + r) * OO + o0 + cc] - mo[s0 + r] - lo[s0 + r];
    }
    __syncthreads();
#pragma unroll
    for (int j = 0; j < 16; ++j) {
        int r = rr + j * 4;
        obsT[(size_t)(o0 + r) * SS + s0 + cc] = tile[cc][r];
    }
}

// ---------------- main sequential-scan kernel ----------------
// one block per batch element, 512 threads = 8 waves, thread == state.
// Per step:
//   TOP: burst-issue ALL 32 P-fragment loads (addresses need only a_t) and
//        the next obsT row; sched_barrier(0) pins them above phase A so the
//        ~4100-cyc L2 drain overlaps phase A's exp/reductions/barriers.
//   phase A: lq, wave max, B1 (lds-only), block max, exp, fp8 p into LDS,
//        wave sum, B2, lse, log_prob update.
//   phase B: 16 ktiles x 4 fp8 MFMAs consuming the burst registers
//        (compiler emits pipelined vmcnt(N) in consumption order), log,
//        write lqprev, B3.
// No ktile skip: a ktile whose p-bytes are all fp8-zero contributes exactly
// 0 through MFMA, so unconditional execution is bit-identical to R5's skip.
__global__ __launch_bounds__(512, 2) void k_main(
    const float* __restrict__ regime, const int* __restrict__ obs,
    const float* __restrict__ rewards, const float* __restrict__ dones,
    const int* __restrict__ actions, const float* __restrict__ prior_logits,
    const unsigned char* __restrict__ PB, const float* __restrict__ obsT,
    const float* __restrict__ policy_logits, const float* __restrict__ r_mu,
    const float* __restrict__ r_logsig, float* __restrict__ out) {
    __shared__ float wrm[8], wrs[8];
    __shared__ unsigned char p8[4 * 144 + 16];  // [quad][16 kt x 8B], 144-pad
    __shared__ float lqprev[SS];
    __shared__ float polT_l[AA * SS];           // 32 KB
    __shared__ int obs_l[TT + 1];
    __shared__ float rew_l[TT + 1];
    __shared__ float done_l[TT + 1];
    __shared__ int act_l[TT];

    const int b = blockIdx.x;
    const int tid = threadIdx.x;
    const int wv = tid >> 6, lane = tid & 63, quad = lane >> 4;
    const int s = tid;

    // ---- one-time preloads ----
    if (tid <= TT) {
        obs_l[tid] = obs[tid * BB + b];
        rew_l[tid] = rewards[tid * BB + b];
        done_l[tid] = dones[tid * BB + b];
        if (tid < TT) act_l[tid] = actions[tid * BB + b];
    }
    {   // inline transposed log-softmax policy -> LDS
        const float4* pr4 = (const float4*)(policy_logits + (size_t)s * AA);
        float4 v0 = pr4[0], v1 = pr4[1], v2 = pr4[2], v3 = pr4[3];
        float xv[16] = {v0.x, v0.y, v0.z, v0.w, v1.x, v1.y, v1.z, v1.w,
                        v2.x, v2.y, v2.z, v2.w, v3.x, v3.y, v3.z, v3.w};
        float mx = xv[0];
#pragma unroll
        for (int i = 1; i < 16; ++i) mx = fmaxf(mx, xv[i]);
        float sm = 0.f;
#pragma unroll
        for (int i = 0; i < 16; ++i) sm += __expf(xv[i] - mx);
        float ls = mx + __logf(sm);
#pragma unroll
        for (int a = 0; a < AA; ++a) polT_l[a * SS + s] = xv[a] - ls;
    }
    const float rm = r_mu[s];
    const float rls = r_logsig[s];
    const float inv_sig = __expf(-rls);
    const float reg = regime[b];

    // inline prior log-softmax (its barriers also publish the preloads)
    float px = prior_logits[s];
    {
        float wm0 = bflyMax(px);
        if (lane == 0) wrm[wv] = wm0;
    }
    lds_barrier();
    float pm = wrm[0];
#pragma unroll
    for (int i = 1; i < 8; ++i) pm = fmaxf(pm, wrm[i]);
    {
        float ws0 = bflySum(__expf(px - pm));
        if (lane == 0) wrs[wv] = ws0;
    }
    lds_barrier();
    float psum = wrs[0];
#pragma unroll
    for (int i = 1; i < 8; ++i) psum += wrs[i];
    const float prior_reg = px - pm - __logf(psum);

    // prefetch obsT row for t=0
    float obsv = obsT[(size_t)obs_l[0] * SS + s];

    float log_prob = 0.f;
    float was_done = 0.f;

    for (int t = 0; t < TT; ++t) {
        const float r = rew_l[t];
        const int a = act_l[t];
        const float d = done_l[t];
        const float done = fmaxf(was_done, d);

        // ---- burst-issue all P-fragment loads for this step ----
        const ulonglong2* PBa =
            (const ulonglong2*)(PB + (size_t)a * (SS * SS)) + 2 * wv * 64 + lane;
        ulonglong2 bfA[16], bfB[16];
#pragma unroll
        for (int kt = 0; kt < 16; ++kt) {
            bfA[kt] = PBa[kt * 16 * 64];
            bfB[kt] = PBa[kt * 16 * 64 + 64];
        }
        // prefetch next obsT row (consumed next iteration)
        float obsv_next = obsT[(size_t)obs_l[t + 1] * SS + s];
        // pin: nothing from phase A may be hoisted above these loads
        __builtin_amdgcn_sched_barrier(0);

        // ---- phase A ----
        float diff = (r - rm) * inv_sig;
        float emis = obsv - 0.5f * diff * diff - rls - 0.5f * LOG2PI;
        float base_in = (t == 0) ? prior_reg : lqprev[s];
        float la = polT_l[a * SS + s];
        if (done == 1.0f || reg == 1.0f) la = 0.f;
        float lq = base_in + emis + la;

        float wmax = bflyMax(lq);
        if (lane == 0) wrm[wv] = wmax;
        lds_barrier();  // B1

        float m = wrm[0];
#pragma unroll
        for (int i = 1; i < 8; ++i) m = fmaxf(m, wrm[i]);

        float ex = __expf(lq - m);
        p8[((s >> 3) & 3) * 144 + (s >> 5) * 8 + (s & 7)] =
            (unsigned char)f32_to_e4m3(ex * 16.0f);
        float wsum = bflySum(ex);
        if (lane == 0) wrs[wv] = wsum;
        lds_barrier();  // B2 (publishes p8)

        float sum = wrs[0];
#pragma unroll
        for (int i = 1; i < 8; ++i) sum += wrs[i];
        float lse = m + __logf(sum);
        float lq_orda = lse * (1.0f - was_done);
        if (!isinf(log_prob)) log_prob += lq_orda;
        was_done = done;

        // ---- phase B: MFMA GEMV; wave wv owns columns 64*wv..64*wv+63 ----
        const float basev = m - lq_orda - LOG4096;
        f32x4 acc0 = {0.f, 0.f, 0.f, 0.f};
        f32x4 acc1 = {0.f, 0.f, 0.f, 0.f};
        f32x4 acc2 = {0.f, 0.f, 0.f, 0.f};
        f32x4 acc3 = {0.f, 0.f, 0.f, 0.f};
#pragma unroll
        for (int kt = 0; kt < 16; ++kt) {
            long af = *(const long long*)(p8 + quad * 144 + kt * 8);
            acc0 = __builtin_amdgcn_mfma_f32_16x16x32_fp8_fp8((long)bfA[kt].x, af, acc0, 0, 0, 0);
            acc1 = __builtin_amdgcn_mfma_f32_16x16x32_fp8_fp8((long)bfA[kt].y, af, acc1, 0, 0, 0);
            acc2 = __builtin_amdgcn_mfma_f32_16x16x32_fp8_fp8((long)bfB[kt].x, af, acc2, 0, 0, 0);
            acc3 = __builtin_amdgcn_mfma_f32_16x16x32_fp8_fp8((long)bfB[kt].y, af, acc3, 0, 0, 0);
        }
        if (lane < 16) {
            lqprev[wv * 64 + lane]      = basev + __logf(acc0[0]);
            lqprev[wv * 64 + 16 + lane] = basev + __logf(acc1[0]);
            lqprev[wv * 64 + 32 + lane] = basev + __logf(acc2[0]);
            lqprev[wv * 64 + 48 + lane] = basev + __logf(acc3[0]);
        }
        lds_barrier();  // B3
        obsv = obsv_next;
    }

    // final step t = TT (no action term, no transition)
    {
        const float r = rew_l[TT];
        float diff = (r - rm) * inv_sig;
        float emis = obsv - 0.5f * diff * diff - rls - 0.5f * LOG2PI;
        float lq = lqprev[s] + emis;
        float wmax = bflyMax(lq);
        if (lane == 0) wrm[wv] = wmax;
        lds_barrier();
        float m = wrm[0];
#pragma unroll
        for (int i = 1; i < 8; ++i) m = fmaxf(m, wrm[i]);
        float wsum = bflySum(__expf(lq - m));
        if (lane == 0) wrs[wv] = wsum;
        lds_barrier();
        float sum = wrs[0];
#pragma unroll
        for (int i = 1; i < 8; ++i) sum += wrs[i];
        float lse = m + __logf(sum);
        float lq_ord = lse * (1.0f - was_done);
        if (!isinf(log_prob)) log_prob += lq_ord;
    }

    if (tid == 0) out[b] = log_prob;
}

// ---------------- launch ----------------
extern "C" void kernel_launch(void* const* d_in, const int* in_sizes, int n_in,
                              void* d_out, int out_size, void* d_ws, size_t ws_size,
                              hipStream_t stream) {
    const float* regime = (const float*)d_in[0];
    const int* obs = (const int*)d_in[1];
    const float* rewards = (const float*)d_in[2];
    const float* dones = (const float*)d_in[3];
    const int* actions = (const int*)d_in[4];
    const float* prior_logits = (const float*)d_in[5];
    const float* trans_logits = (const float*)d_in[6];
    const float* obs_logits = (const float*)d_in[7];
    const float* policy_logits = (const float*)d_in[8];
    const float* r_mu = (const float*)d_in[9];
    const float* r_logsig = (const float*)d_in[10];
    float* out = (float*)d_out;

    char* ws = (char*)d_ws;
    unsigned char* PB = (unsigned char*)ws;                    // A*S*S fp8 = 4 MB
    float* obsT = (float*)(ws + (size_t)AA * SS * SS);         // O*S fp32 = 8 MB
    float* mo = (float*)(ws + (size_t)AA * SS * SS + (size_t)OO * SS * 4);  // S
    float* lo = mo + SS;                                       // S

    k_pack<<<256, 1024, 0, stream>>>(trans_logits, PB);
    k_obs_stats<<<SS, 256, 0, stream>>>(obs_logits, mo, lo);
    k_obsT<<<(OO / 64) * (SS / 64), 256, 0, stream>>>(obs_logits, mo, lo, obsT);
    k_main<<<BB, 512, 0, stream>>>(regime, obs, rewards, dones, actions, prior_logits,
                                   PB, obsT, policy_logits, r_mu, r_logsig, out);
}